// Round 17
// baseline (379.822 us; speedup 1.0000x reference)
//
#include <hip/hip_runtime.h>
#include <hip/hip_bf16.h>

#define HD 64        // hidden == out dim
#define CH 8192      // edges per bin1 block
#define BKT_SHIFT 10 // 1024 nodes per bucket
#define SRC_BITS 17  // N=100000 < 2^17 -> {dstlocal:10 | src:17} fits in 27 bits
#define MAXBLK 256   // >= NBLK = ceil(E/CH) = 196

typedef __attribute__((ext_vector_type(8))) short bf16x8;
typedef __attribute__((ext_vector_type(4))) float f32x4;

__device__ inline unsigned short f2bf(float x) {
  unsigned u = __float_as_uint(x);
  unsigned r = u + 0x7FFF + ((u >> 16) & 1);
  return (unsigned short)(r >> 16);
}
__device__ inline float bf2f(unsigned short h) {
  return __uint_as_float(((unsigned)h) << 16);
}

// ---------------- W fragment prep: lane-indexed MFMA B-frags in global -------
// Wf layout: frag (ks,f) for lane L at [((ks*4+f)*64 + L)*8 .. +8) shorts ->
// gemm reads are 16B/lane fully coalesced; array is tiny (L2-broadcast).
__global__ __launch_bounds__(256) void k_wprep(const float* __restrict__ W1,
                                               const float* __restrict__ W2,
                                               unsigned short* __restrict__ Wf1,
                                               unsigned short* __restrict__ Wf2hi,
                                               unsigned short* __restrict__ Wf2lo) {
  int idx = blockIdx.x * blockDim.x + threadIdx.x;
  if (idx < 256 * 64) {
    int k = idx >> 6, c = idx & 63;
    float w = W1[idx];
    int ks = k >> 5, r = k & 31, h2 = r >> 3, j = r & 7;
    int f = c >> 4, r16c = c & 15;
    int pos = (((ks * 4 + f) * 64) + h2 * 16 + r16c) * 8 + j;
    Wf1[pos] = f2bf(w);
  } else if (idx < 256 * 64 + 64 * 64) {
    int i2 = idx - 256 * 64;
    int k = i2 >> 6, c = i2 & 63;
    float w = W2[i2];
    int ks = k >> 5, r = k & 31, h2 = r >> 3, j = r & 7;
    int f = c >> 4, r16c = c & 15;
    int pos = (((ks * 4 + f) * 64) + h2 * 16 + r16c) * 8 + j;
    unsigned short hi = f2bf(w);
    Wf2hi[pos] = hi;
    Wf2lo[pos] = f2bf(w - bf2f(hi));
  }
}

// ---------------- binning pass 1 (both graphs): block-local bucket sort ------
__global__ __launch_bounds__(256) void k_bin1(const int* __restrict__ src0,
                                              const int* __restrict__ dst0,
                                              const int* __restrict__ src1,
                                              const int* __restrict__ dst1,
                                              int* __restrict__ tmp,
                                              int* __restrict__ counts,
                                              int* __restrict__ offsets,
                                              int NB, int NBLK, int E) {
  __shared__ int hist[128];
  __shared__ int pref[128];
  __shared__ int lofs[128];
  __shared__ int stage[CH];  // 32 KB
  const int g = blockIdx.x / NBLK;
  const int blk = blockIdx.x % NBLK;
  const int* __restrict__ src = g ? src1 : src0;
  const int* __restrict__ dst = g ? dst1 : dst0;
  int* __restrict__ tmpg = tmp + (size_t)g * NBLK * CH;
  int* __restrict__ cntg = counts + (size_t)g * NB * NBLK;
  int* __restrict__ offg = offsets + (size_t)g * NB * NBLK;
  const int e0 = blk * CH;
  const int len = min(CH, E - e0);
  const int t = threadIdx.x;

  for (int i = t; i < 128; i += 256) hist[i] = 0;
  __syncthreads();
  int dreg[CH / 256];
#pragma unroll
  for (int it = 0; it < CH / 256; ++it) {
    int i = t + it * 256;
    if (i < len) {
      int d = dst[e0 + i];
      dreg[it] = d;
      atomicAdd(&hist[d >> BKT_SHIFT], 1);
    }
  }
  __syncthreads();
  if (t < 128) pref[t] = hist[t];
  __syncthreads();
  for (int off = 1; off < 128; off <<= 1) {
    int v = 0;
    if (t < 128 && t >= off) v = pref[t - off];
    __syncthreads();
    if (t < 128) pref[t] += v;
    __syncthreads();
  }
  if (t < NB) {
    int ex = pref[t] - hist[t];
    lofs[t] = ex;
    cntg[t * NBLK + blk] = hist[t];   // [bucket][block]
    offg[t * NBLK + blk] = ex;
  }
  __syncthreads();
#pragma unroll
  for (int it = 0; it < CH / 256; ++it) {
    int i = t + it * 256;
    if (i < len) {
      int d = dreg[it], s = src[e0 + i];
      int slot = atomicAdd(&lofs[d >> BKT_SHIFT], 1);
      stage[slot] = ((d & ((1 << BKT_SHIFT) - 1)) << SRC_BITS) | s;
    }
  }
  __syncthreads();
  int nv = len >> 2;
  for (int i = t; i < nv; i += 256) ((int4*)(tmpg + e0))[i] = ((const int4*)stage)[i];
  for (int i = (nv << 2) + t; i < len; i += 256) tmpg[e0 + i] = stage[i];
}

// ---------------- bucket totals + exclusive scan (one block per graph) -------
__global__ __launch_bounds__(128) void k_bscan(const int* __restrict__ counts,
                                               int* __restrict__ bucket_base,
                                               int* __restrict__ row_start,
                                               int NB, int NBLK, int N, int E) {
  __shared__ int sh[128];
  const int g = blockIdx.x;
  const int* __restrict__ cntg = counts + (size_t)g * NB * NBLK;
  int* __restrict__ bbg = bucket_base + g * (NB + 1);
  int* __restrict__ rsg = row_start + (size_t)g * (N + 1);
  int t = threadIdx.x;
  int v = 0;
  if (t < NB) {
    const int* p = cntg + t * NBLK;
    for (int i = 0; i < NBLK; ++i) v += p[i];
  }
  sh[t] = v;
  __syncthreads();
  for (int off = 1; off < 128; off <<= 1) {
    int x = (t >= off) ? sh[t - off] : 0;
    __syncthreads();
    sh[t] += x;
    __syncthreads();
  }
  if (t < NB) bbg[t] = sh[t] - v;  // exclusive
  if (t == 0) {
    bbg[NB] = E;
    rsg[N] = E;
  }
}

// ---------------- merged bin2 (both graphs): hist + scan + place -------------
__global__ __launch_bounds__(1024) void k_bin2m(const int* __restrict__ tmp,
                                                const int* __restrict__ counts,
                                                const int* __restrict__ offsets,
                                                const int* __restrict__ bucket_base,
                                                int* __restrict__ row_start,
                                                float* __restrict__ dinv,
                                                int* __restrict__ recs, int N, int NB,
                                                int NBLK, int E) {
  __shared__ int h[1 << BKT_SHIFT];
  __shared__ int lcur[1 << BKT_SHIFT];
  __shared__ int scnt[MAXBLK], soff[MAXBLK];
  const int g = blockIdx.x / NB;
  const int b = blockIdx.x % NB;
  const int* __restrict__ tmpg = tmp + (size_t)g * NBLK * CH;
  const int* __restrict__ cntg = counts + (size_t)g * NB * NBLK;
  const int* __restrict__ offg = offsets + (size_t)g * NB * NBLK;
  const int* __restrict__ bbg = bucket_base + g * (NB + 1);
  int* __restrict__ rsg = row_start + (size_t)g * (N + 1);
  float* __restrict__ dig = dinv + (size_t)g * N;
  int* __restrict__ recg = recs + (size_t)g * E;
  const int t = threadIdx.x;
  const int node0 = b << BKT_SHIFT;
  const int lane = t & 63, w = t >> 6;

  h[t] = 0;
  for (int i = t; i < NBLK; i += 1024) {
    scnt[i] = cntg[b * NBLK + i];
    soff[i] = offg[b * NBLK + i];
  }
  __syncthreads();
  for (int blk = w; blk < NBLK; blk += 16) {
    int cnt = scnt[blk];
    const int* p = tmpg + blk * CH + soff[blk];
    for (int j = lane; j < cnt; j += 64) atomicAdd(&h[p[j] >> SRC_BITS], 1);
  }
  __syncthreads();
  int deg = h[t];
  __syncthreads();
  for (int off = 1; off < 1024; off <<= 1) {
    int x = (t >= off) ? h[t - off] : 0;
    __syncthreads();
    h[t] += x;
    __syncthreads();
  }
  int base = bbg[b] + h[t] - deg;
  lcur[t] = base;
  int n = node0 + t;
  if (n < N) {
    rsg[n] = base;
    dig[n] = rsqrtf((float)deg + 1.0f);
  }
  __syncthreads();
  for (int blk = w; blk < NBLK; blk += 16) {
    int cnt = scnt[blk];
    const int* p = tmpg + blk * CH + soff[blk];
    for (int j = lane; j < cnt; j += 64) {
      int rec = p[j];
      int d = rec >> SRC_BITS;
      int s = rec & ((1 << SRC_BITS) - 1);
      int slot = atomicAdd(&lcur[d], 1);
      recg[slot] = s;
    }
  }
}

// ---------------- GEMM via MFMA: NO LDS, NO barriers -------------------------
// 512 threads = 8 waves, 128 rows/block. A direct from global (per-lane);
// B fragments direct from precomputed global Wf (16B/lane coalesced, L2-hot).
// Occupancy is wave-slot limited; every load is independent of LDS/barriers.
template <int K, int A_BF16, int B_LO>
__global__ __launch_bounds__(512) void k_gemm(const void* __restrict__ Xv0,
                                              const void* __restrict__ Xv1,
                                              const unsigned short* __restrict__ Wfh,
                                              const unsigned short* __restrict__ Wfl,
                                              unsigned short* __restrict__ Hb, int N,
                                              int gPer) {
  constexpr int NKS = K / 32;
  const int tid = threadIdx.x;
  const int g = blockIdx.x / gPer;
  const int bblk = blockIdx.x % gPer;
  const void* __restrict__ Xv = g ? Xv1 : Xv0;

  const int lane = tid & 63;
  const int wv = tid >> 6;
  const int r16 = lane & 15;
  const int half = lane >> 4;
  const int row = bblk * 128 + wv * 16 + r16;
  const int rowc = min(row, N - 1);  // clamp; stores guarded

  f32x4 acc[4];
#pragma unroll
  for (int f = 0; f < 4; ++f) acc[f] = (f32x4){0.f, 0.f, 0.f, 0.f};

#pragma unroll
  for (int ks = 0; ks < NKS; ++ks) {
    bf16x8 ahi;
    if constexpr (A_BF16) {
      union { uint4 u; bf16x8 v; } au;
      au.u = *(const uint4*)((const unsigned short*)Xv + (size_t)rowc * K + ks * 32 + half * 8);
      ahi = au.v;
    } else {
      const float* xp = (const float*)Xv + (size_t)rowc * K + ks * 32 + half * 8;
      float4 a0 = *(const float4*)xp;
      float4 a1 = *(const float4*)(xp + 4);
      union { __hip_bfloat162 h[4]; bf16x8 v; } cu;
      cu.h[0] = __float22bfloat162_rn(make_float2(a0.x, a0.y));
      cu.h[1] = __float22bfloat162_rn(make_float2(a0.z, a0.w));
      cu.h[2] = __float22bfloat162_rn(make_float2(a1.x, a1.y));
      cu.h[3] = __float22bfloat162_rn(make_float2(a1.z, a1.w));
      ahi = cu.v;
    }
#pragma unroll
    for (int f = 0; f < 4; ++f) {
      bf16x8 bh = *(const bf16x8*)&Wfh[(((ks * 4 + f) * 64) + lane) * 8];
      acc[f] = __builtin_amdgcn_mfma_f32_16x16x32_bf16(ahi, bh, acc[f], 0, 0, 0);
      if constexpr (B_LO) {
        bf16x8 bl = *(const bf16x8*)&Wfl[(((ks * 4 + f) * 64) + lane) * 8];
        acc[f] = __builtin_amdgcn_mfma_f32_16x16x32_bf16(ahi, bl, acc[f], 0, 0, 0);
      }
    }
  }

  const int orow0 = bblk * 128 + wv * 16 + half * 4;
#pragma unroll
  for (int f = 0; f < 4; ++f) {
#pragma unroll
    for (int rg = 0; rg < 4; ++rg) {
      int orow = orow0 + rg;
      if (orow < N) Hb[((size_t)g * N + orow) * HD + f * 16 + r16] = f2bf(acc[f][rg]);
    }
  }
}

// ---------------- Aggregation (both graphs): 16 lanes/node, uint2 gathers ----
template <int OUTBF16>
__global__ __launch_bounds__(256) void k_agg(const unsigned short* __restrict__ Hb,
                                             const int* __restrict__ recs,
                                             const int* __restrict__ row_start,
                                             const float* __restrict__ dinv,
                                             const float* __restrict__ bias,
                                             void* __restrict__ outv, int N, int E,
                                             int relu) {
  const int t = threadIdx.x;
  const int nglob = (blockIdx.x * blockDim.x + t) >> 4;
  const int lane16 = t & 15;
  if (nglob >= 2 * N) return;
  const int g = nglob >= N;
  const int node = nglob - g * N;
  const int* __restrict__ rsg = row_start + (size_t)g * (N + 1);
  const int* __restrict__ R = recs + (size_t)g * E;
  const float* __restrict__ dig = dinv + (size_t)g * N;
  const unsigned short* __restrict__ Hbg = Hb + (size_t)g * N * HD;

  const int c0 = lane16 * 4;
  float di = dig[node];
  float a0, a1, a2, a3;
  {
    uint2 h = *(const uint2*)&Hbg[(size_t)node * HD + c0];
    float dd = di * di;
    a0 = bf2f((unsigned short)(h.x & 0xffff)) * dd;
    a1 = bf2f((unsigned short)(h.x >> 16)) * dd;
    a2 = bf2f((unsigned short)(h.y & 0xffff)) * dd;
    a3 = bf2f((unsigned short)(h.y >> 16)) * dd;
  }
  const int beg = rsg[node], end = rsg[node + 1];
  int e = beg;
  for (; e + 8 <= end; e += 8) {
    int s[8];
    uint2 gg[8];
    float n[8];
#pragma unroll
    for (int j = 0; j < 8; ++j) s[j] = R[e + j];
#pragma unroll
    for (int j = 0; j < 8; ++j) {
      gg[j] = *(const uint2*)&Hbg[(size_t)s[j] * HD + c0];
      n[j] = dig[s[j]];
    }
#pragma unroll
    for (int j = 0; j < 8; ++j) {
      float nn = n[j] * di;
      a0 = fmaf(bf2f((unsigned short)(gg[j].x & 0xffff)), nn, a0);
      a1 = fmaf(bf2f((unsigned short)(gg[j].x >> 16)), nn, a1);
      a2 = fmaf(bf2f((unsigned short)(gg[j].y & 0xffff)), nn, a2);
      a3 = fmaf(bf2f((unsigned short)(gg[j].y >> 16)), nn, a3);
    }
  }
  for (; e < end; ++e) {
    int s = R[e];
    uint2 gg = *(const uint2*)&Hbg[(size_t)s * HD + c0];
    float nn = dig[s] * di;
    a0 = fmaf(bf2f((unsigned short)(gg.x & 0xffff)), nn, a0);
    a1 = fmaf(bf2f((unsigned short)(gg.x >> 16)), nn, a1);
    a2 = fmaf(bf2f((unsigned short)(gg.y & 0xffff)), nn, a2);
    a3 = fmaf(bf2f((unsigned short)(gg.y >> 16)), nn, a3);
  }
  float4 bv = *(const float4*)&bias[c0];
  a0 += bv.x; a1 += bv.y; a2 += bv.z; a3 += bv.w;
  if (relu) {
    a0 = fmaxf(a0, 0.f); a1 = fmaxf(a1, 0.f);
    a2 = fmaxf(a2, 0.f); a3 = fmaxf(a3, 0.f);
  }
  if (OUTBF16) {
    uint2 o;
    o.x = ((unsigned)f2bf(a1) << 16) | f2bf(a0);
    o.y = ((unsigned)f2bf(a3) << 16) | f2bf(a2);
    *(uint2*)&((unsigned short*)outv)[(size_t)nglob * HD + c0] = o;
  } else {
    *(float4*)&((float*)outv)[(size_t)nglob * HD + c0] = make_float4(a0, a1, a2, a3);
  }
}

// ---------------- zscore (both graphs) ----------------

__global__ void k_colstats(const float* __restrict__ H, float* __restrict__ stats, int N,
                           int gridPer) {
  __shared__ float ss[256], sq[256];
  const int g = blockIdx.x / gridPer;
  const int blk = blockIdx.x % gridPer;
  const float* __restrict__ Hg = H + (size_t)g * N * HD;
  float* __restrict__ st = stats + g * 128;
  int t = threadIdx.x;
  int col = t & 63, grp = t >> 6;
  float s = 0.f, q = 0.f;
  for (int row = blk * 4 + grp; row < N; row += gridPer * 4) {
    float v = Hg[(size_t)row * HD + col];
    s += v;
    q += v * v;
  }
  ss[t] = s;
  sq[t] = q;
  __syncthreads();
  if (t < 64) {
    s = ss[t] + ss[t + 64] + ss[t + 128] + ss[t + 192];
    q = sq[t] + sq[t + 64] + sq[t + 128] + sq[t + 192];
    atomicAdd(&st[t], s);
    atomicAdd(&st[64 + t], q);
  }
}

__global__ void k_normalize(float* __restrict__ H, const float* __restrict__ stats, int N) {
  int i = blockIdx.x * blockDim.x + threadIdx.x;
  int total = 2 * N * HD;
  if (i >= total) return;
  int col = i & 63;
  const float* st = stats + (i >= N * HD ? 128 : 0);
  float sum = st[col], sumsq = st[64 + col];
  float mean = sum / (float)N;
  float var = (sumsq - sum * sum / (float)N) / (float)(N - 1);
  float r = rsqrtf(var);
  H[i] = (H[i] - mean) * r;
}

// ---------------- launch ----------------

extern "C" void kernel_launch(void* const* d_in, const int* in_sizes, int n_in,
                              void* d_out, int out_size, void* d_ws, size_t ws_size,
                              hipStream_t stream) {
  const int IN_DIM = 256;
  const float* X1 = (const float*)d_in[0];
  const float* X2 = (const float*)d_in[2];
  const int* EI1 = (const int*)d_in[1];
  const int* EI2 = (const int*)d_in[3];
  const float* W1 = (const float*)d_in[4];
  const float* b1 = (const float*)d_in[5];
  const float* W2 = (const float*)d_in[6];
  const float* b2 = (const float*)d_in[7];
  const int N = in_sizes[0] / IN_DIM;
  const int E = in_sizes[1] / 2;
  const int NB = (N + (1 << BKT_SHIFT) - 1) >> BKT_SHIFT;  // 98
  const int NBLK = (E + CH - 1) / CH;                      // 196

  char* ws = (char*)d_ws;
  size_t off = 0;
  auto carve = [&](size_t bytes) -> char* {
    char* p = ws + off;
    off += (bytes + 255) & ~(size_t)255;
    return p;
  };
  unsigned short* Hb = (unsigned short*)carve((size_t)2 * N * HD * 2);  // both graphs
  int* tmp = (int*)carve((size_t)2 * NBLK * CH * 4);
  int* recs = (int*)carve((size_t)2 * E * 4);
  char* zero_base = carve(256 * 4);  // stats[2][128]
  float* stats = (float*)zero_base;
  int* row_start = (int*)carve((size_t)2 * (N + 1) * 4);
  float* dinv = (float*)carve((size_t)2 * N * 4);
  int* bucket_base = (int*)carve((size_t)2 * (NB + 1) * 4);
  int* counts = (int*)carve((size_t)2 * NB * NBLK * 4);
  int* offsets = (int*)carve((size_t)2 * NB * NBLK * 4);
  unsigned short* Wf1 = (unsigned short*)carve(256 * 64 * 2);
  unsigned short* Wf2hi = (unsigned short*)carve(64 * 64 * 2);
  unsigned short* Wf2lo = (unsigned short*)carve(64 * 64 * 2);
  unsigned short* bufAgg = (unsigned short*)d_out;  // alias: dead before agg2 writes
  (void)ws_size; (void)n_in; (void)out_size;

  const int T = 256;
  const int gPer1 = (N + 127) / 128;
  const int gPer2 = (2 * N + 127) / 128;
  const int gAgg = (2 * N * 16 + T - 1) / T;
  const int gCS = 512;
  const int gElem = (2 * N * HD + T - 1) / T;
  const int gWp = (256 * 64 + 64 * 64 + T - 1) / T;  // 80

  (void)hipMemsetAsync(zero_base, 0, 256 * 4, stream);
  k_wprep<<<gWp, T, 0, stream>>>(W1, W2, Wf1, Wf2hi, Wf2lo);
  k_bin1<<<2 * NBLK, T, 0, stream>>>(EI1, EI1 + E, EI2, EI2 + E, tmp, counts, offsets,
                                     NB, NBLK, E);
  k_bscan<<<2, 128, 0, stream>>>(counts, bucket_base, row_start, NB, NBLK, N, E);
  k_bin2m<<<2 * NB, 1024, 0, stream>>>(tmp, counts, offsets, bucket_base, row_start,
                                       dinv, recs, N, NB, NBLK, E);

  // layer 1 (both graphs): h = relu(agg(x @ W1) + b1) -> bufAgg (bf16, in d_out)
  k_gemm<256, 0, 0><<<2 * gPer1, 512, 0, stream>>>(X1, X2, Wf1, nullptr, Hb, N, gPer1);
  k_agg<1><<<gAgg, T, 0, stream>>>(Hb, recs, row_start, dinv, b1, bufAgg, N, E, 1);
  // layer 2 (both graphs as one 2N-row GEMM): h2 = agg(h1 @ W2) + b2 -> d_out f32
  k_gemm<64, 1, 1><<<gPer2, 512, 0, stream>>>(bufAgg, bufAgg, Wf2hi, Wf2lo, Hb, 2 * N, gPer2);
  k_agg<0><<<gAgg, T, 0, stream>>>(Hb, recs, row_start, dinv, b2, d_out, N, E, 0);

  // zscore in place on d_out (per graph)
  k_colstats<<<2 * gCS, T, 0, stream>>>((float*)d_out, stats, N, gCS);
  k_normalize<<<gElem, T, 0, stream>>>((float*)d_out, stats, N);
}

// Round 18
// 363.945 us; speedup vs baseline: 1.0436x; 1.0436x over previous
//
#include <hip/hip_runtime.h>
#include <hip/hip_bf16.h>

#define HD 64        // hidden == out dim
#define CH 8192      // edges per bin1 block
#define BKT_SHIFT 10 // 1024 nodes per bucket
#define SRC_BITS 17  // N=100000 < 2^17 -> {dstlocal:10 | src:17} fits in 27 bits
#define MAXBLK 256   // >= NBLK = ceil(E/CH) = 196

typedef __attribute__((ext_vector_type(8))) short bf16x8;
typedef __attribute__((ext_vector_type(4))) float f32x4;

typedef __attribute__((address_space(1))) const unsigned int* gas_ptr;
typedef __attribute__((address_space(3))) unsigned int* las_ptr;

__device__ inline void gl_lds16(const void* g, void* l) {
  __builtin_amdgcn_global_load_lds((gas_ptr)g, (las_ptr)l, 16, 0, 0);
}

__device__ inline unsigned short f2bf(float x) {
  unsigned u = __float_as_uint(x);
  unsigned r = u + 0x7FFF + ((u >> 16) & 1);
  return (unsigned short)(r >> 16);
}
__device__ inline float bf2f(unsigned short h) {
  return __uint_as_float(((unsigned)h) << 16);
}

// ---------------- W fragment prep: lane-indexed MFMA B-frags in global -------
__global__ __launch_bounds__(256) void k_wprep(const float* __restrict__ W1,
                                               const float* __restrict__ W2,
                                               unsigned short* __restrict__ Wf1,
                                               unsigned short* __restrict__ Wf2hi,
                                               unsigned short* __restrict__ Wf2lo) {
  int idx = blockIdx.x * blockDim.x + threadIdx.x;
  if (idx < 256 * 64) {
    int k = idx >> 6, c = idx & 63;
    float w = W1[idx];
    int ks = k >> 5, r = k & 31, h2 = r >> 3, j = r & 7;
    int f = c >> 4, r16c = c & 15;
    int pos = (((ks * 4 + f) * 64) + h2 * 16 + r16c) * 8 + j;
    Wf1[pos] = f2bf(w);
  } else if (idx < 256 * 64 + 64 * 64) {
    int i2 = idx - 256 * 64;
    int k = i2 >> 6, c = i2 & 63;
    float w = W2[i2];
    int ks = k >> 5, r = k & 31, h2 = r >> 3, j = r & 7;
    int f = c >> 4, r16c = c & 15;
    int pos = (((ks * 4 + f) * 64) + h2 * 16 + r16c) * 8 + j;
    unsigned short hi = f2bf(w);
    Wf2hi[pos] = hi;
    Wf2lo[pos] = f2bf(w - bf2f(hi));
  }
}

// ---------------- binning pass 1 (both graphs): block-local bucket sort ------
__global__ __launch_bounds__(256) void k_bin1(const int* __restrict__ src0,
                                              const int* __restrict__ dst0,
                                              const int* __restrict__ src1,
                                              const int* __restrict__ dst1,
                                              int* __restrict__ tmp,
                                              int* __restrict__ counts,
                                              int* __restrict__ offsets,
                                              int NB, int NBLK, int E) {
  __shared__ int hist[128];
  __shared__ int pref[128];
  __shared__ int lofs[128];
  __shared__ int stage[CH];  // 32 KB
  const int g = blockIdx.x / NBLK;
  const int blk = blockIdx.x % NBLK;
  const int* __restrict__ src = g ? src1 : src0;
  const int* __restrict__ dst = g ? dst1 : dst0;
  int* __restrict__ tmpg = tmp + (size_t)g * NBLK * CH;
  int* __restrict__ cntg = counts + (size_t)g * NB * NBLK;
  int* __restrict__ offg = offsets + (size_t)g * NB * NBLK;
  const int e0 = blk * CH;
  const int len = min(CH, E - e0);
  const int t = threadIdx.x;

  for (int i = t; i < 128; i += 256) hist[i] = 0;
  __syncthreads();
  int dreg[CH / 256];
#pragma unroll
  for (int it = 0; it < CH / 256; ++it) {
    int i = t + it * 256;
    if (i < len) {
      int d = dst[e0 + i];
      dreg[it] = d;
      atomicAdd(&hist[d >> BKT_SHIFT], 1);
    }
  }
  __syncthreads();
  if (t < 128) pref[t] = hist[t];
  __syncthreads();
  for (int off = 1; off < 128; off <<= 1) {
    int v = 0;
    if (t < 128 && t >= off) v = pref[t - off];
    __syncthreads();
    if (t < 128) pref[t] += v;
    __syncthreads();
  }
  if (t < NB) {
    int ex = pref[t] - hist[t];
    lofs[t] = ex;
    cntg[t * NBLK + blk] = hist[t];   // [bucket][block]
    offg[t * NBLK + blk] = ex;
  }
  __syncthreads();
#pragma unroll
  for (int it = 0; it < CH / 256; ++it) {
    int i = t + it * 256;
    if (i < len) {
      int d = dreg[it], s = src[e0 + i];
      int slot = atomicAdd(&lofs[d >> BKT_SHIFT], 1);
      stage[slot] = ((d & ((1 << BKT_SHIFT) - 1)) << SRC_BITS) | s;
    }
  }
  __syncthreads();
  int nv = len >> 2;
  for (int i = t; i < nv; i += 256) ((int4*)(tmpg + e0))[i] = ((const int4*)stage)[i];
  for (int i = (nv << 2) + t; i < len; i += 256) tmpg[e0 + i] = stage[i];
}

// ---------------- bucket totals + exclusive scan (one block per graph) -------
__global__ __launch_bounds__(128) void k_bscan(const int* __restrict__ counts,
                                               int* __restrict__ bucket_base,
                                               int* __restrict__ row_start,
                                               int NB, int NBLK, int N, int E) {
  __shared__ int sh[128];
  const int g = blockIdx.x;
  const int* __restrict__ cntg = counts + (size_t)g * NB * NBLK;
  int* __restrict__ bbg = bucket_base + g * (NB + 1);
  int* __restrict__ rsg = row_start + (size_t)g * (N + 1);
  int t = threadIdx.x;
  int v = 0;
  if (t < NB) {
    const int* p = cntg + t * NBLK;
    for (int i = 0; i < NBLK; ++i) v += p[i];
  }
  sh[t] = v;
  __syncthreads();
  for (int off = 1; off < 128; off <<= 1) {
    int x = (t >= off) ? sh[t - off] : 0;
    __syncthreads();
    sh[t] += x;
    __syncthreads();
  }
  if (t < NB) bbg[t] = sh[t] - v;  // exclusive
  if (t == 0) {
    bbg[NB] = E;
    rsg[N] = E;
  }
}

// ---------------- merged bin2 (both graphs): hist + scan + place -------------
__global__ __launch_bounds__(1024) void k_bin2m(const int* __restrict__ tmp,
                                                const int* __restrict__ counts,
                                                const int* __restrict__ offsets,
                                                const int* __restrict__ bucket_base,
                                                int* __restrict__ row_start,
                                                float* __restrict__ dinv,
                                                int* __restrict__ recs, int N, int NB,
                                                int NBLK, int E) {
  __shared__ int h[1 << BKT_SHIFT];
  __shared__ int lcur[1 << BKT_SHIFT];
  __shared__ int scnt[MAXBLK], soff[MAXBLK];
  const int g = blockIdx.x / NB;
  const int b = blockIdx.x % NB;
  const int* __restrict__ tmpg = tmp + (size_t)g * NBLK * CH;
  const int* __restrict__ cntg = counts + (size_t)g * NB * NBLK;
  const int* __restrict__ offg = offsets + (size_t)g * NB * NBLK;
  const int* __restrict__ bbg = bucket_base + g * (NB + 1);
  int* __restrict__ rsg = row_start + (size_t)g * (N + 1);
  float* __restrict__ dig = dinv + (size_t)g * N;
  int* __restrict__ recg = recs + (size_t)g * E;
  const int t = threadIdx.x;
  const int node0 = b << BKT_SHIFT;
  const int lane = t & 63, w = t >> 6;

  h[t] = 0;
  for (int i = t; i < NBLK; i += 1024) {
    scnt[i] = cntg[b * NBLK + i];
    soff[i] = offg[b * NBLK + i];
  }
  __syncthreads();
  for (int blk = w; blk < NBLK; blk += 16) {
    int cnt = scnt[blk];
    const int* p = tmpg + blk * CH + soff[blk];
    for (int j = lane; j < cnt; j += 64) atomicAdd(&h[p[j] >> SRC_BITS], 1);
  }
  __syncthreads();
  int deg = h[t];
  __syncthreads();
  for (int off = 1; off < 1024; off <<= 1) {
    int x = (t >= off) ? h[t - off] : 0;
    __syncthreads();
    h[t] += x;
    __syncthreads();
  }
  int base = bbg[b] + h[t] - deg;
  lcur[t] = base;
  int n = node0 + t;
  if (n < N) {
    rsg[n] = base;
    dig[n] = rsqrtf((float)deg + 1.0f);
  }
  __syncthreads();
  for (int blk = w; blk < NBLK; blk += 16) {
    int cnt = scnt[blk];
    const int* p = tmpg + blk * CH + soff[blk];
    for (int j = lane; j < cnt; j += 64) {
      int rec = p[j];
      int d = rec >> SRC_BITS;
      int s = rec & ((1 << SRC_BITS) - 1);
      int slot = atomicAdd(&lcur[d], 1);
      recg[slot] = s;
    }
  }
}

// ---------------- GEMM1 fp32 K=256: A via global_load_lds (dbuf), B global ----
// 256 thr = 4 waves, BM=64 rows. A chunk KC=64 floats (16KB) double-buffered
// (32KB LDS -> 5 blocks/CU). LDS linear; swizzle applied on GLOBAL source in
// 16B units (u' = (u&8)|((u&7)^(r&7))), inverted on fragment reads -> ~2-way
// conflicts. B frags from global Wf1 (L2-hot, 16B/lane coalesced).
__global__ __launch_bounds__(256) void k_gemm1(const float* __restrict__ X0,
                                               const float* __restrict__ X1,
                                               const unsigned short* __restrict__ Wf1,
                                               unsigned short* __restrict__ Hb, int N,
                                               int gPer) {
  __shared__ float sA[2][64 * 64];  // 2 x 16KB
  const int tid = threadIdx.x;
  const int g = blockIdx.x / gPer;
  const int bblk = blockIdx.x % gPer;
  const float* __restrict__ Xv = g ? X1 : X0;
  const int row0 = bblk * 64;
  const int lane = tid & 63;
  const int wv = tid >> 6;
  const int r16 = lane & 15;
  const int half = lane >> 4;
  const int rowL = wv * 16 + r16;

  auto STAGE = [&](int b, int c) {
#pragma unroll
    for (int i = 0; i < 4; ++i) {
      int slot = tid + i * 256;  // 0..1023 : 64 rows x 16 units
      int r = slot >> 4, u = slot & 15;
      int su = (u & 8) | ((u & 7) ^ (r & 7));
      int gr = min(row0 + r, N - 1);
      gl_lds16(Xv + (size_t)gr * 256 + c * 64 + su * 4, (char*)&sA[b][0] + slot * 16);
    }
  };

  f32x4 acc[4];
#pragma unroll
  for (int f = 0; f < 4; ++f) acc[f] = (f32x4){0.f, 0.f, 0.f, 0.f};

  STAGE(0, 0);
  for (int c = 0; c < 4; ++c) {
    const int buf = c & 1;
    if (c < 3) STAGE(buf ^ 1, c + 1);
    __syncthreads();  // drains DMA (vmcnt0); cross-block occupancy hides this
#pragma unroll
    for (int ks2 = 0; ks2 < 2; ++ks2) {
      const int ksg = c * 2 + ks2;
      int v0 = ks2 * 8 + half * 2;
      int p0 = (v0 & 8) | ((v0 & 7) ^ (rowL & 7));
      int p1 = ((v0 + 1) & 8) | (((v0 + 1) & 7) ^ (rowL & 7));
      float4 a0 = *(const float4*)((const char*)&sA[buf][0] + (rowL * 16 + p0) * 16);
      float4 a1 = *(const float4*)((const char*)&sA[buf][0] + (rowL * 16 + p1) * 16);
      union { __hip_bfloat162 h[4]; bf16x8 v; } cu;
      cu.h[0] = __float22bfloat162_rn(make_float2(a0.x, a0.y));
      cu.h[1] = __float22bfloat162_rn(make_float2(a0.z, a0.w));
      cu.h[2] = __float22bfloat162_rn(make_float2(a1.x, a1.y));
      cu.h[3] = __float22bfloat162_rn(make_float2(a1.z, a1.w));
      bf16x8 ahi = cu.v;
#pragma unroll
      for (int f = 0; f < 4; ++f) {
        bf16x8 bh = *(const bf16x8*)&Wf1[(((ksg * 4 + f) * 64) + lane) * 8];
        acc[f] = __builtin_amdgcn_mfma_f32_16x16x32_bf16(ahi, bh, acc[f], 0, 0, 0);
      }
    }
    __syncthreads();  // protect buf before re-stage
  }

  const int orow0 = row0 + wv * 16 + half * 4;
#pragma unroll
  for (int f = 0; f < 4; ++f) {
#pragma unroll
    for (int rg = 0; rg < 4; ++rg) {
      int orow = orow0 + rg;
      if (orow < N) Hb[((size_t)g * N + orow) * HD + f * 16 + r16] = f2bf(acc[f][rg]);
    }
  }
}

// ---------------- GEMM2 bf16 K=64 (rows = 2N): A staged once (8KB), B global --
__global__ __launch_bounds__(256) void k_gemm2(const unsigned short* __restrict__ Xb,
                                               const unsigned short* __restrict__ Wfh,
                                               const unsigned short* __restrict__ Wfl,
                                               unsigned short* __restrict__ Hb, int M) {
  __shared__ unsigned short sA[64 * 64];  // 8KB
  const int tid = threadIdx.x;
  const int row0 = blockIdx.x * 64;
  const int lane = tid & 63;
  const int wv = tid >> 6;
  const int r16 = lane & 15;
  const int half = lane >> 4;
  const int rowL = wv * 16 + r16;

#pragma unroll
  for (int i = 0; i < 2; ++i) {
    int slot = tid + i * 256;  // 0..511 : 64 rows x 8 units
    int r = slot >> 3, u = slot & 7;
    int su = u ^ (r & 7);
    int gr = min(row0 + r, M - 1);
    gl_lds16(Xb + (size_t)gr * 64 + su * 8, (char*)sA + slot * 16);
  }
  __syncthreads();

  f32x4 acc[4];
#pragma unroll
  for (int f = 0; f < 4; ++f) acc[f] = (f32x4){0.f, 0.f, 0.f, 0.f};

#pragma unroll
  for (int ks = 0; ks < 2; ++ks) {
    int v = ks * 4 + half;
    int p = v ^ (rowL & 7);
    bf16x8 ahi = *(const bf16x8*)((const char*)sA + (rowL * 8 + p) * 16);
#pragma unroll
    for (int f = 0; f < 4; ++f) {
      bf16x8 bh = *(const bf16x8*)&Wfh[(((ks * 4 + f) * 64) + lane) * 8];
      bf16x8 bl = *(const bf16x8*)&Wfl[(((ks * 4 + f) * 64) + lane) * 8];
      acc[f] = __builtin_amdgcn_mfma_f32_16x16x32_bf16(ahi, bh, acc[f], 0, 0, 0);
      acc[f] = __builtin_amdgcn_mfma_f32_16x16x32_bf16(ahi, bl, acc[f], 0, 0, 0);
    }
  }

  const int orow0 = row0 + wv * 16 + half * 4;
#pragma unroll
  for (int f = 0; f < 4; ++f) {
#pragma unroll
    for (int rg = 0; rg < 4; ++rg) {
      int orow = orow0 + rg;
      if (orow < M) Hb[(size_t)orow * HD + f * 16 + r16] = f2bf(acc[f][rg]);
    }
  }
}

// ---------------- Aggregation (both graphs): 16 lanes/node, uint2 gathers ----
template <int OUTBF16>
__global__ __launch_bounds__(256) void k_agg(const unsigned short* __restrict__ Hb,
                                             const int* __restrict__ recs,
                                             const int* __restrict__ row_start,
                                             const float* __restrict__ dinv,
                                             const float* __restrict__ bias,
                                             void* __restrict__ outv, int N, int E,
                                             int relu) {
  const int t = threadIdx.x;
  const int nglob = (blockIdx.x * blockDim.x + t) >> 4;
  const int lane16 = t & 15;
  if (nglob >= 2 * N) return;
  const int g = nglob >= N;
  const int node = nglob - g * N;
  const int* __restrict__ rsg = row_start + (size_t)g * (N + 1);
  const int* __restrict__ R = recs + (size_t)g * E;
  const float* __restrict__ dig = dinv + (size_t)g * N;
  const unsigned short* __restrict__ Hbg = Hb + (size_t)g * N * HD;

  const int c0 = lane16 * 4;
  float di = dig[node];
  float a0, a1, a2, a3;
  {
    uint2 h = *(const uint2*)&Hbg[(size_t)node * HD + c0];
    float dd = di * di;
    a0 = bf2f((unsigned short)(h.x & 0xffff)) * dd;
    a1 = bf2f((unsigned short)(h.x >> 16)) * dd;
    a2 = bf2f((unsigned short)(h.y & 0xffff)) * dd;
    a3 = bf2f((unsigned short)(h.y >> 16)) * dd;
  }
  const int beg = rsg[node], end = rsg[node + 1];
  int e = beg;
  for (; e + 8 <= end; e += 8) {
    int s[8];
    uint2 gg[8];
    float n[8];
#pragma unroll
    for (int j = 0; j < 8; ++j) s[j] = R[e + j];
#pragma unroll
    for (int j = 0; j < 8; ++j) {
      gg[j] = *(const uint2*)&Hbg[(size_t)s[j] * HD + c0];
      n[j] = dig[s[j]];
    }
#pragma unroll
    for (int j = 0; j < 8; ++j) {
      float nn = n[j] * di;
      a0 = fmaf(bf2f((unsigned short)(gg[j].x & 0xffff)), nn, a0);
      a1 = fmaf(bf2f((unsigned short)(gg[j].x >> 16)), nn, a1);
      a2 = fmaf(bf2f((unsigned short)(gg[j].y & 0xffff)), nn, a2);
      a3 = fmaf(bf2f((unsigned short)(gg[j].y >> 16)), nn, a3);
    }
  }
  for (; e < end; ++e) {
    int s = R[e];
    uint2 gg = *(const uint2*)&Hbg[(size_t)s * HD + c0];
    float nn = dig[s] * di;
    a0 = fmaf(bf2f((unsigned short)(gg.x & 0xffff)), nn, a0);
    a1 = fmaf(bf2f((unsigned short)(gg.x >> 16)), nn, a1);
    a2 = fmaf(bf2f((unsigned short)(gg.y & 0xffff)), nn, a2);
    a3 = fmaf(bf2f((unsigned short)(gg.y >> 16)), nn, a3);
  }
  float4 bv = *(const float4*)&bias[c0];
  a0 += bv.x; a1 += bv.y; a2 += bv.z; a3 += bv.w;
  if (relu) {
    a0 = fmaxf(a0, 0.f); a1 = fmaxf(a1, 0.f);
    a2 = fmaxf(a2, 0.f); a3 = fmaxf(a3, 0.f);
  }
  if (OUTBF16) {
    uint2 o;
    o.x = ((unsigned)f2bf(a1) << 16) | f2bf(a0);
    o.y = ((unsigned)f2bf(a3) << 16) | f2bf(a2);
    *(uint2*)&((unsigned short*)outv)[(size_t)nglob * HD + c0] = o;
  } else {
    *(float4*)&((float*)outv)[(size_t)nglob * HD + c0] = make_float4(a0, a1, a2, a3);
  }
}

// ---------------- zscore (both graphs) ----------------

__global__ void k_colstats(const float* __restrict__ H, float* __restrict__ stats, int N,
                           int gridPer) {
  __shared__ float ss[256], sq[256];
  const int g = blockIdx.x / gridPer;
  const int blk = blockIdx.x % gridPer;
  const float* __restrict__ Hg = H + (size_t)g * N * HD;
  float* __restrict__ st = stats + g * 128;
  int t = threadIdx.x;
  int col = t & 63, grp = t >> 6;
  float s = 0.f, q = 0.f;
  for (int row = blk * 4 + grp; row < N; row += gridPer * 4) {
    float v = Hg[(size_t)row * HD + col];
    s += v;
    q += v * v;
  }
  ss[t] = s;
  sq[t] = q;
  __syncthreads();
  if (t < 64) {
    s = ss[t] + ss[t + 64] + ss[t + 128] + ss[t + 192];
    q = sq[t] + sq[t + 64] + sq[t + 128] + sq[t + 192];
    atomicAdd(&st[t], s);
    atomicAdd(&st[64 + t], q);
  }
}

__global__ void k_normalize(float* __restrict__ H, const float* __restrict__ stats, int N) {
  int i = blockIdx.x * blockDim.x + threadIdx.x;
  int total = 2 * N * HD;
  if (i >= total) return;
  int col = i & 63;
  const float* st = stats + (i >= N * HD ? 128 : 0);
  float sum = st[col], sumsq = st[64 + col];
  float mean = sum / (float)N;
  float var = (sumsq - sum * sum / (float)N) / (float)(N - 1);
  float r = rsqrtf(var);
  H[i] = (H[i] - mean) * r;
}

// ---------------- launch ----------------

extern "C" void kernel_launch(void* const* d_in, const int* in_sizes, int n_in,
                              void* d_out, int out_size, void* d_ws, size_t ws_size,
                              hipStream_t stream) {
  const int IN_DIM = 256;
  const float* X1 = (const float*)d_in[0];
  const float* X2 = (const float*)d_in[2];
  const int* EI1 = (const int*)d_in[1];
  const int* EI2 = (const int*)d_in[3];
  const float* W1 = (const float*)d_in[4];
  const float* b1 = (const float*)d_in[5];
  const float* W2 = (const float*)d_in[6];
  const float* b2 = (const float*)d_in[7];
  const int N = in_sizes[0] / IN_DIM;
  const int E = in_sizes[1] / 2;
  const int NB = (N + (1 << BKT_SHIFT) - 1) >> BKT_SHIFT;  // 98
  const int NBLK = (E + CH - 1) / CH;                      // 196

  char* ws = (char*)d_ws;
  size_t off = 0;
  auto carve = [&](size_t bytes) -> char* {
    char* p = ws + off;
    off += (bytes + 255) & ~(size_t)255;
    return p;
  };
  unsigned short* Hb = (unsigned short*)carve((size_t)2 * N * HD * 2);  // both graphs
  int* tmp = (int*)carve((size_t)2 * NBLK * CH * 4);
  int* recs = (int*)carve((size_t)2 * E * 4);
  char* zero_base = carve(256 * 4);  // stats[2][128]
  float* stats = (float*)zero_base;
  int* row_start = (int*)carve((size_t)2 * (N + 1) * 4);
  float* dinv = (float*)carve((size_t)2 * N * 4);
  int* bucket_base = (int*)carve((size_t)2 * (NB + 1) * 4);
  int* counts = (int*)carve((size_t)2 * NB * NBLK * 4);
  int* offsets = (int*)carve((size_t)2 * NB * NBLK * 4);
  unsigned short* Wf1 = (unsigned short*)carve(256 * 64 * 2);
  unsigned short* Wf2hi = (unsigned short*)carve(64 * 64 * 2);
  unsigned short* Wf2lo = (unsigned short*)carve(64 * 64 * 2);
  unsigned short* bufAgg = (unsigned short*)d_out;  // alias: dead before agg2 writes
  (void)ws_size; (void)n_in; (void)out_size;

  const int T = 256;
  const int gPer1 = (N + 63) / 64;        // 64-row blocks, per graph
  const int gG2 = (2 * N + 63) / 64;      // gemm2 over 2N rows
  const int gAgg = (2 * N * 16 + T - 1) / T;
  const int gCS = 512;
  const int gElem = (2 * N * HD + T - 1) / T;
  const int gWp = (256 * 64 + 64 * 64 + T - 1) / T;  // 80

  (void)hipMemsetAsync(zero_base, 0, 256 * 4, stream);
  k_wprep<<<gWp, T, 0, stream>>>(W1, W2, Wf1, Wf2hi, Wf2lo);
  k_bin1<<<2 * NBLK, T, 0, stream>>>(EI1, EI1 + E, EI2, EI2 + E, tmp, counts, offsets,
                                     NB, NBLK, E);
  k_bscan<<<2, 128, 0, stream>>>(counts, bucket_base, row_start, NB, NBLK, N, E);
  k_bin2m<<<2 * NB, 1024, 0, stream>>>(tmp, counts, offsets, bucket_base, row_start,
                                       dinv, recs, N, NB, NBLK, E);

  // layer 1 (both graphs): h = relu(agg(x @ W1) + b1) -> bufAgg (bf16, in d_out)
  k_gemm1<<<2 * gPer1, T, 0, stream>>>(X1, X2, Wf1, Hb, N, gPer1);
  k_agg<1><<<gAgg, T, 0, stream>>>(Hb, recs, row_start, dinv, b1, bufAgg, N, E, 1);
  // layer 2 (both graphs as one 2N-row GEMM): h2 = agg(h1 @ W2) + b2 -> d_out f32
  k_gemm2<<<gG2, T, 0, stream>>>(bufAgg, Wf2hi, Wf2lo, Hb, 2 * N);
  k_agg<0><<<gAgg, T, 0, stream>>>(Hb, recs, row_start, dinv, b2, d_out, N, E, 0);

  // zscore in place on d_out (per graph)
  k_colstats<<<2 * gCS, T, 0, stream>>>((float*)d_out, stats, N, gCS);
  k_normalize<<<gElem, T, 0, stream>>>((float*)d_out, stats, N);
}